// Round 1
// baseline (732.494 us; speedup 1.0000x reference)
//
#include <hip/hip_runtime.h>
#include <cstdint>
#include <cstddef>

#define N_NODES   50000
#define N_EDGES   600000
#define DIM       128
#define NLAYERS   4
#define N_GRAPHS  64
#define N_PATIENTS 50

typedef __attribute__((ext_vector_type(8))) __bf16        bf16x8;
typedef __attribute__((ext_vector_type(4))) float         f32x4;
typedef __attribute__((ext_vector_type(4))) unsigned int  u32x4;
typedef __attribute__((ext_vector_type(8))) unsigned short u16x8;

__device__ inline unsigned short f2bf(float f) {
    unsigned u = __builtin_bit_cast(unsigned, f);
    u += 0x7FFFu + ((u >> 16) & 1u);   // round-to-nearest-even
    return (unsigned short)(u >> 16);
}

// ---------------- CSR build ----------------

__global__ void k_count(const int* __restrict__ ei, int* __restrict__ counts) {
    int e = blockIdx.x * 256 + threadIdx.x;
    if (e < N_EDGES) atomicAdd(&counts[ei[N_EDGES + e]], 1);
}

__global__ void k_scan_a(const int* __restrict__ counts, int* __restrict__ incl,
                         int* __restrict__ bsums, int n) {
    __shared__ int s[256];
    int i = blockIdx.x * 256 + threadIdx.x;
    int v = (i < n) ? counts[i] : 0;
    s[threadIdx.x] = v;
    __syncthreads();
    for (int off = 1; off < 256; off <<= 1) {
        int t = (threadIdx.x >= off) ? s[threadIdx.x - off] : 0;
        __syncthreads();
        s[threadIdx.x] += t;
        __syncthreads();
    }
    if (i < n) incl[i] = s[threadIdx.x];
    if (threadIdx.x == 255) bsums[blockIdx.x] = s[255];
}

__global__ void k_scan_b(int* __restrict__ bsums, int nb) {
    __shared__ int s[256];
    int t = threadIdx.x;
    int v = (t < nb) ? bsums[t] : 0;
    s[t] = v;
    __syncthreads();
    for (int off = 1; off < 256; off <<= 1) {
        int u = (t >= off) ? s[t - off] : 0;
        __syncthreads();
        s[t] += u;
        __syncthreads();
    }
    if (t < nb) bsums[t] = s[t];
}

__global__ void k_scan_c(const int* __restrict__ counts, const int* __restrict__ incl,
                         const int* __restrict__ bsums, int* __restrict__ row_ptr,
                         int* __restrict__ cursor, int n) {
    int i = blockIdx.x * 256 + threadIdx.x;
    if (i < n) {
        int off = blockIdx.x ? bsums[blockIdx.x - 1] : 0;
        int ex  = incl[i] - counts[i] + off;
        row_ptr[i] = ex;
        cursor[i]  = ex;
        if (i == n - 1) row_ptr[n] = incl[i] + off;
    }
}

__global__ void k_fill(const int* __restrict__ ei, int* __restrict__ cursor,
                       int* __restrict__ esorted) {
    int e = blockIdx.x * 256 + threadIdx.x;
    if (e < N_EDGES) {
        int d   = ei[N_EDGES + e];
        int pos = atomicAdd(&cursor[d], 1);
        esorted[pos] = ei[e];
    }
}

// ---------------- W precombine: Wt[l][c][k] = bf16(Wcat[k][c]) ----------------

__global__ void k_wt(const float* __restrict__ Wroot, const float* __restrict__ Wrel,
                     unsigned short* __restrict__ Wt) {
    int idx = blockIdx.x * 256 + threadIdx.x;   // l*32768 + c*256 + k
    if (idx < NLAYERS * DIM * 256) {
        int l = idx >> 15;
        int c = (idx >> 8) & 127;
        int k = idx & 255;
        float v = (k < 128) ? Wroot[l * 16384 + k * 128 + c]
                            : Wrel[l * 16384 + (k - 128) * 128 + c];
        Wt[idx] = f2bf(v);
    }
}

// ---------------- fused layer: gather-agg + GEMM + LN + ELU + residual ----------------

__global__ __launch_bounds__(256) void k_layer(
    const float* __restrict__ xin, float* __restrict__ xout,
    const int* __restrict__ row_ptr, const int* __restrict__ esrc,
    const unsigned short* __restrict__ Wt,     // [128][256] bf16, linear
    const float* __restrict__ bconv, const float* __restrict__ gamma,
    const float* __restrict__ beta,
    const float* __restrict__ bW, const float* __restrict__ bb,
    float* __restrict__ boundary, int last)
{
    __shared__ __align__(16) unsigned short x2s[64 * 256];   // 32 KB, XOR-swizzled
    const int tid     = threadIdx.x;
    const int rowbase = blockIdx.x * 64;

    // phase 1a: x rows -> bf16 LDS cols [0,128)
    {
        int r = tid >> 2, q = tid & 3;
        int grow = rowbase + r;
        int rx = (r & 7) << 4;
        if (grow < N_NODES) {
            const float* xp = xin + (size_t)grow * DIM + q * 32;
            #pragma unroll
            for (int c = 0; c < 4; c++) {
                f32x4 v0 = *(const f32x4*)(xp + c * 8);
                f32x4 v1 = *(const f32x4*)(xp + c * 8 + 4);
                u16x8 o = { f2bf(v0[0]), f2bf(v0[1]), f2bf(v0[2]), f2bf(v0[3]),
                            f2bf(v1[0]), f2bf(v1[1]), f2bf(v1[2]), f2bf(v1[3]) };
                int byteoff = (r * 512 + q * 64 + c * 16) ^ rx;
                *(u16x8*)((char*)x2s + byteoff) = o;
            }
        } else {
            u16x8 z = { 0, 0, 0, 0, 0, 0, 0, 0 };
            #pragma unroll
            for (int c = 0; c < 4; c++) {
                int byteoff = (r * 512 + q * 64 + c * 16) ^ rx;
                *(u16x8*)((char*)x2s + byteoff) = z;
            }
        }
    }

    // phase 1b: CSR neighbor-sum -> bf16 LDS cols [128,256). Wave w owns rows [w*16, w*16+16).
    {
        int w = tid >> 6, lane = tid & 63;
        for (int i = w * 16; i < w * 16 + 16; ++i) {
            int grow = rowbase + i;
            float ax = 0.f, ay = 0.f;
            if (grow < N_NODES) {
                int beg = row_ptr[grow], end = row_ptr[grow + 1];
                float2 a0 = make_float2(0.f, 0.f), a1 = make_float2(0.f, 0.f);
                int e = beg;
                for (; e + 1 < end; e += 2) {
                    int s0 = esrc[e], s1 = esrc[e + 1];
                    float2 v0 = *(const float2*)(xin + (size_t)s0 * DIM + lane * 2);
                    float2 v1 = *(const float2*)(xin + (size_t)s1 * DIM + lane * 2);
                    a0.x += v0.x; a0.y += v0.y;
                    a1.x += v1.x; a1.y += v1.y;
                }
                if (e < end) {
                    int s0 = esrc[e];
                    float2 v0 = *(const float2*)(xin + (size_t)s0 * DIM + lane * 2);
                    a0.x += v0.x; a0.y += v0.y;
                }
                ax = a0.x + a1.x; ay = a0.y + a1.y;
            }
            unsigned pack = (unsigned)f2bf(ax) | ((unsigned)f2bf(ay) << 16);
            int byteoff = (i * 512 + 256 + lane * 4) ^ ((i & 7) << 4);
            *(unsigned*)((char*)x2s + byteoff) = pack;
        }
    }
    __syncthreads();

    // phase 2: [64x256] @ [256x128] via mfma_f32_16x16x32_bf16. Wave w -> rows [w*16, w*16+16).
    int lane = tid & 63, w = tid >> 6;
    int colb = lane & 15, kg = lane >> 4;

    u32x4 araw[8];
    {
        int row  = w * 16 + colb;
        int base = row * 512 + kg * 16;
        int rx   = (row & 7) << 4;
        #pragma unroll
        for (int ks = 0; ks < 8; ks++) {
            int byteoff = (base + ks * 64) ^ rx;
            araw[ks] = *(const u32x4*)((const char*)x2s + byteoff);
        }
    }

    f32x4 acc[8];
    #pragma unroll
    for (int cb = 0; cb < 8; cb++) acc[cb] = 0.0f;

    #pragma unroll
    for (int cb = 0; cb < 8; cb++) {
        const unsigned short* wp = Wt + ((cb * 16 + colb) * 256 + kg * 8);
        #pragma unroll
        for (int ks = 0; ks < 8; ks++) {
            u32x4 braw = *(const u32x4*)(wp + ks * 32);
            acc[cb] = __builtin_amdgcn_mfma_f32_16x16x32_bf16(
                __builtin_bit_cast(bf16x8, araw[ks]),
                __builtin_bit_cast(bf16x8, braw), acc[cb], 0, 0, 0);
        }
    }

    // epilogue: +bias, LayerNorm (16-lane shfl reduce), ELU, residual, fused boundary head
    #pragma unroll
    for (int j = 0; j < 4; j++) {
        float hv[8];
        float sum = 0.f, sq = 0.f;
        #pragma unroll
        for (int cb = 0; cb < 8; cb++) {
            float h = acc[cb][j] + bconv[cb * 16 + colb];
            hv[cb] = h; sum += h; sq += h * h;
        }
        #pragma unroll
        for (int m = 1; m < 16; m <<= 1) {
            sum += __shfl_xor(sum, m);
            sq  += __shfl_xor(sq, m);
        }
        float mean = sum * (1.f / 128.f);
        float var  = sq * (1.f / 128.f) - mean * mean;
        float rs   = rsqrtf(var + 1e-5f);
        int grow = rowbase + w * 16 + kg * 4 + j;     // uniform across the 16-lane group
        if (grow < N_NODES) {
            float bl = 0.f;
            #pragma unroll
            for (int cb = 0; cb < 8; cb++) {
                int col  = cb * 16 + colb;
                float hn = (hv[cb] - mean) * rs * gamma[col] + beta[col];
                hn = hn > 0.f ? hn : (expf(hn) - 1.f);
                float xo = hn + xin[(size_t)grow * DIM + col];
                xout[(size_t)grow * DIM + col] = xo;
                bl += xo * bW[col];
            }
            if (last) {
                #pragma unroll
                for (int m = 1; m < 16; m <<= 1) bl += __shfl_xor(bl, m);
                if (colb == 0) boundary[grow] = bl + bb[0];
            }
        }
    }
}

// ---------------- mean-pool per graph (batch is sorted) ----------------

__global__ void k_pool(const float* __restrict__ x, const int* __restrict__ batch,
                       float* __restrict__ pooled, int* __restrict__ gcount) {
    __shared__ float s[128];
    int g = blockIdx.x >> 2, q = blockIdx.x & 3;
    int lo = 0, hi = N_NODES;
    while (lo < hi) { int m = (lo + hi) >> 1; if (batch[m] < g) lo = m + 1; else hi = m; }
    int s0 = lo;
    lo = 0; hi = N_NODES;
    while (lo < hi) { int m = (lo + hi) >> 1; if (batch[m] < g + 1) lo = m + 1; else hi = m; }
    int e0  = lo;
    int len = e0 - s0;
    int r0 = s0 + (len * q) / 4;
    int r1 = s0 + (len * (q + 1)) / 4;
    int col = threadIdx.x & 127, half = threadIdx.x >> 7;
    float acc = 0.f;
    for (int r = r0 + half; r < r1; r += 2) acc += x[(size_t)r * DIM + col];
    if (half) s[col] = acc;
    __syncthreads();
    if (!half) {
        acc += s[col];
        atomicAdd(&pooled[g * DIM + col], acc);
    }
    if (q == 0 && threadIdx.x == 0) gcount[g] = len;
}

// ---------------- domain head MLP (tiny) ----------------

__global__ __launch_bounds__(256) void k_mlp(
    const float* __restrict__ pooled, const int* __restrict__ gcount,
    const float* __restrict__ W1, const float* __restrict__ b1,
    const float* __restrict__ W2, const float* __restrict__ b2,
    float* __restrict__ out)
{
    __shared__ float pm[64 * 128];
    __shared__ float h1[64 * 64];
    int tid = threadIdx.x;
    for (int idx = tid; idx < 64 * 128; idx += 256) {
        int g = idx >> 7;
        float cnt = (float)gcount[g];
        if (cnt < 1.f) cnt = 1.f;
        pm[idx] = pooled[idx] / cnt;
    }
    __syncthreads();
    {
        int i = tid & 63, jg = tid >> 6;
        for (int jj = 0; jj < 16; jj++) {
            int j = jg * 16 + jj;
            float s = b1[j];
            for (int k = 0; k < 128; k++) s += pm[i * 128 + k] * W1[k * 64 + j];
            h1[i * 64 + j] = s > 0.f ? s : (expf(s) - 1.f);
        }
    }
    __syncthreads();
    for (int o = tid; o < 64 * N_PATIENTS; o += 256) {
        int i = o / N_PATIENTS, p = o - i * N_PATIENTS;
        float s = b2[p];
        for (int k = 0; k < 64; k++) s += h1[i * 64 + k] * W2[k * N_PATIENTS + p];
        out[o] = s;
    }
}

// ---------------- launch ----------------

extern "C" void kernel_launch(void* const* d_in, const int* in_sizes, int n_in,
                              void* d_out, int out_size, void* d_ws, size_t ws_size,
                              hipStream_t stream) {
    const float* x     = (const float*)d_in[0];
    const int*   ei    = (const int*)d_in[1];
    const int*   batch = (const int*)d_in[2];
    const float* Wroot = (const float*)d_in[3];
    const float* Wrel  = (const float*)d_in[4];
    const float* bconv = (const float*)d_in[5];
    const float* gamma = (const float*)d_in[6];
    const float* beta  = (const float*)d_in[7];
    const float* bW    = (const float*)d_in[8];
    const float* bb    = (const float*)d_in[9];
    const float* W1    = (const float*)d_in[10];
    const float* b1    = (const float*)d_in[11];
    const float* W2    = (const float*)d_in[12];
    const float* b2    = (const float*)d_in[13];
    float* out = (float*)d_out;

    char* ws = (char*)d_ws;
    size_t off = 0;
    auto alloc = [&](size_t bytes) -> char* {
        char* p = ws + off;
        off += (bytes + 255) & ~(size_t)255;
        return p;
    };
    float*          xA      = (float*)alloc((size_t)N_NODES * DIM * 4);
    float*          xB      = (float*)alloc((size_t)N_NODES * DIM * 4);
    unsigned short* Wt      = (unsigned short*)alloc((size_t)NLAYERS * DIM * 256 * 2);
    int*            counts  = (int*)alloc((size_t)N_NODES * 4);
    int*            incl    = (int*)alloc((size_t)N_NODES * 4);
    int*            row_ptr = (int*)alloc((size_t)(N_NODES + 1) * 4);
    int*            cursor  = (int*)alloc((size_t)N_NODES * 4);
    int*            esorted = (int*)alloc((size_t)N_EDGES * 4);
    int*            bsums   = (int*)alloc(256 * 4);
    float*          pooled  = (float*)alloc((size_t)N_GRAPHS * DIM * 4);
    int*            gcount  = (int*)alloc((size_t)N_GRAPHS * 4);
    (void)ws_size; (void)in_sizes; (void)n_in; (void)out_size;

    hipMemsetAsync(counts, 0, (size_t)N_NODES * 4, stream);
    hipMemsetAsync(pooled, 0, (size_t)N_GRAPHS * DIM * 4, stream);

    k_wt<<<(NLAYERS * DIM * 256 + 255) / 256, 256, 0, stream>>>(Wroot, Wrel, Wt);
    k_count<<<(N_EDGES + 255) / 256, 256, 0, stream>>>(ei, counts);
    int nb = (N_NODES + 255) / 256;
    k_scan_a<<<nb, 256, 0, stream>>>(counts, incl, bsums, N_NODES);
    k_scan_b<<<1, 256, 0, stream>>>(bsums, nb);
    k_scan_c<<<nb, 256, 0, stream>>>(counts, incl, bsums, row_ptr, cursor, N_NODES);
    k_fill<<<(N_EDGES + 255) / 256, 256, 0, stream>>>(ei, cursor, esorted);

    int lgrid = (N_NODES + 63) / 64;
    const float* xi = x;
    float* xo = xA;
    for (int l = 0; l < NLAYERS; l++) {
        int last = (l == NLAYERS - 1);
        k_layer<<<lgrid, 256, 0, stream>>>(xi, xo, row_ptr, esorted, Wt + (size_t)l * DIM * 256,
                                           bconv + l * DIM, gamma + l * DIM, beta + l * DIM,
                                           bW, bb, out, last);
        xi = xo;
        xo = (xo == xA) ? xB : xA;
    }
    const float* xf = xi;
    k_pool<<<N_GRAPHS * 4, 256, 0, stream>>>(xf, batch, pooled, gcount);
    k_mlp<<<1, 256, 0, stream>>>(pooled, gcount, W1, b1, W2, b2, out + N_NODES);
}

// Round 2
// 451.562 us; speedup vs baseline: 1.6221x; 1.6221x over previous
//
#include <hip/hip_runtime.h>
#include <cstdint>
#include <cstddef>

#define N_NODES   50000
#define N_EDGES   600000
#define DIM       128
#define NLAYERS   4
#define N_GRAPHS  64
#define N_PATIENTS 50

typedef __attribute__((ext_vector_type(8))) __bf16        bf16x8;
typedef __attribute__((ext_vector_type(4))) float         f32x4;
typedef __attribute__((ext_vector_type(4))) unsigned int  u32x4;
typedef __attribute__((ext_vector_type(8))) unsigned short u16x8;

__device__ inline unsigned short f2bf(float f) {
    unsigned u = __builtin_bit_cast(unsigned, f);
    u += 0x7FFFu + ((u >> 16) & 1u);   // round-to-nearest-even
    return (unsigned short)(u >> 16);
}

__device__ inline float bf2f(unsigned short s) {
    return __builtin_bit_cast(float, (unsigned)s << 16);
}

__device__ inline f32x4 bf4f(ushort4 u) {
    f32x4 r;
    r.x = bf2f(u.x); r.y = bf2f(u.y); r.z = bf2f(u.z); r.w = bf2f(u.w);
    return r;
}

// ---------------- CSR build ----------------

__global__ void k_count(const int* __restrict__ ei, int* __restrict__ counts) {
    int e = blockIdx.x * 256 + threadIdx.x;
    if (e < N_EDGES) atomicAdd(&counts[ei[N_EDGES + e]], 1);
}

__global__ void k_scan_a(const int* __restrict__ counts, int* __restrict__ incl,
                         int* __restrict__ bsums, int n) {
    __shared__ int s[256];
    int i = blockIdx.x * 256 + threadIdx.x;
    int v = (i < n) ? counts[i] : 0;
    s[threadIdx.x] = v;
    __syncthreads();
    for (int off = 1; off < 256; off <<= 1) {
        int t = (threadIdx.x >= off) ? s[threadIdx.x - off] : 0;
        __syncthreads();
        s[threadIdx.x] += t;
        __syncthreads();
    }
    if (i < n) incl[i] = s[threadIdx.x];
    if (threadIdx.x == 255) bsums[blockIdx.x] = s[255];
}

__global__ void k_scan_b(int* __restrict__ bsums, int nb) {
    __shared__ int s[256];
    int t = threadIdx.x;
    int v = (t < nb) ? bsums[t] : 0;
    s[t] = v;
    __syncthreads();
    for (int off = 1; off < 256; off <<= 1) {
        int u = (t >= off) ? s[t - off] : 0;
        __syncthreads();
        s[t] += u;
        __syncthreads();
    }
    if (t < nb) bsums[t] = s[t];
}

__global__ void k_scan_c(const int* __restrict__ counts, const int* __restrict__ incl,
                         const int* __restrict__ bsums, int* __restrict__ row_ptr,
                         int* __restrict__ cursor, int n) {
    int i = blockIdx.x * 256 + threadIdx.x;
    if (i < n) {
        int off = blockIdx.x ? bsums[blockIdx.x - 1] : 0;
        int ex  = incl[i] - counts[i] + off;
        row_ptr[i] = ex;
        cursor[i]  = ex;
        if (i == n - 1) row_ptr[n] = incl[i] + off;
    }
}

__global__ void k_fill(const int* __restrict__ ei, int* __restrict__ cursor,
                       int* __restrict__ esorted) {
    int e = blockIdx.x * 256 + threadIdx.x;
    if (e < N_EDGES) {
        int d   = ei[N_EDGES + e];
        int pos = atomicAdd(&cursor[d], 1);
        esorted[pos] = ei[e];
    }
}

// ---------------- x -> bf16 copy ----------------

__global__ void k_prep(const float* __restrict__ x, unsigned short* __restrict__ xb) {
    int idx = blockIdx.x * 256 + threadIdx.x;        // one u16x8 per thread
    if (idx < N_NODES * DIM / 8) {
        f32x4 v0 = *(const f32x4*)(x + (size_t)idx * 8);
        f32x4 v1 = *(const f32x4*)(x + (size_t)idx * 8 + 4);
        u16x8 o = { f2bf(v0[0]), f2bf(v0[1]), f2bf(v0[2]), f2bf(v0[3]),
                    f2bf(v1[0]), f2bf(v1[1]), f2bf(v1[2]), f2bf(v1[3]) };
        *(u16x8*)(xb + (size_t)idx * 8) = o;
    }
}

// ---------------- W precombine: Wt[l][c][k] = bf16(Wcat[k][c]) ----------------

__global__ void k_wt(const float* __restrict__ Wroot, const float* __restrict__ Wrel,
                     unsigned short* __restrict__ Wt) {
    int idx = blockIdx.x * 256 + threadIdx.x;   // l*32768 + c*256 + k
    if (idx < NLAYERS * DIM * 256) {
        int l = idx >> 15;
        int c = (idx >> 8) & 127;
        int k = idx & 255;
        float v = (k < 128) ? Wroot[l * 16384 + k * 128 + c]
                            : Wrel[l * 16384 + (k - 128) * 128 + c];
        Wt[idx] = f2bf(v);
    }
}

// ---------------- fused layer ----------------

__global__ __launch_bounds__(256) void k_layer(
    const float* __restrict__ xin, float* __restrict__ xout,
    const unsigned short* __restrict__ xb,        // bf16 copy of xin
    unsigned short* __restrict__ xbnext,          // bf16 copy of xout (may be null)
    const int* __restrict__ row_ptr, const int* __restrict__ esrc,
    const unsigned short* __restrict__ Wt,        // [128][256] bf16, linear
    const float* __restrict__ bconv, const float* __restrict__ gamma,
    const float* __restrict__ beta,
    const float* __restrict__ bW, const float* __restrict__ bb,
    float* __restrict__ boundary, int last)
{
    __shared__ __align__(16) unsigned short x2s[64 * 256];   // 32 KB, XOR-swizzled
    const int tid     = threadIdx.x;
    const int rowbase = blockIdx.x * 64;

    // phase 1a: x rows (bf16) -> LDS cols [0,128)
    {
        int r = tid >> 2, q = tid & 3;           // r row, q covers 32 cols
        int grow = rowbase + r;
        int rx = (r & 7) << 4;
        if (grow < N_NODES) {
            const unsigned short* xp = xb + (size_t)grow * DIM + q * 32;
            #pragma unroll
            for (int c = 0; c < 4; c++) {
                u16x8 v = *(const u16x8*)(xp + c * 8);
                int byteoff = (r * 512 + q * 64 + c * 16) ^ rx;
                *(u16x8*)((char*)x2s + byteoff) = v;
            }
        } else {
            u16x8 z = { 0, 0, 0, 0, 0, 0, 0, 0 };
            #pragma unroll
            for (int c = 0; c < 4; c++) {
                int byteoff = (r * 512 + q * 64 + c * 16) ^ rx;
                *(u16x8*)((char*)x2s + byteoff) = z;
            }
        }
    }

    // phase 1b: CSR neighbor-sum. One row per 16-lane group, 4 rows in parallel
    // per wave, 4 edges unrolled -> 8 independent 8B loads in flight.
    {
        int w = tid >> 6, lane = tid & 63;
        int kg = lane >> 4, li = lane & 15;
        #pragma unroll
        for (int rr = 0; rr < 4; ++rr) {
            int i = w * 16 + kg * 4 + rr;         // local row
            int grow = rowbase + i;
            f32x4 a0 = 0.f, a1 = 0.f, b0 = 0.f, b1 = 0.f;
            int beg = 0, end = 0;
            if (grow < N_NODES) { beg = row_ptr[grow]; end = row_ptr[grow + 1]; }
            int e = beg;
            for (; e + 3 < end; e += 4) {
                int s0 = esrc[e], s1 = esrc[e + 1], s2 = esrc[e + 2], s3 = esrc[e + 3];
                const unsigned short* p0 = xb + (size_t)s0 * DIM + li * 4;
                const unsigned short* p1 = xb + (size_t)s1 * DIM + li * 4;
                const unsigned short* p2 = xb + (size_t)s2 * DIM + li * 4;
                const unsigned short* p3 = xb + (size_t)s3 * DIM + li * 4;
                ushort4 u0 = *(const ushort4*)p0;
                ushort4 u1 = *(const ushort4*)(p0 + 64);
                ushort4 u2 = *(const ushort4*)p1;
                ushort4 u3 = *(const ushort4*)(p1 + 64);
                ushort4 u4 = *(const ushort4*)p2;
                ushort4 u5 = *(const ushort4*)(p2 + 64);
                ushort4 u6 = *(const ushort4*)p3;
                ushort4 u7 = *(const ushort4*)(p3 + 64);
                a0 += bf4f(u0); a1 += bf4f(u1);
                b0 += bf4f(u2); b1 += bf4f(u3);
                a0 += bf4f(u4); a1 += bf4f(u5);
                b0 += bf4f(u6); b1 += bf4f(u7);
            }
            for (; e < end; ++e) {
                int s0 = esrc[e];
                const unsigned short* p0 = xb + (size_t)s0 * DIM + li * 4;
                ushort4 u0 = *(const ushort4*)p0;
                ushort4 u1 = *(const ushort4*)(p0 + 64);
                a0 += bf4f(u0); a1 += bf4f(u1);
            }
            a0 += b0; a1 += b1;
            // store agg row i: cols [li*4..+3] and [64+li*4..+3] as bf16
            unsigned w0 = (unsigned)f2bf(a0.x) | ((unsigned)f2bf(a0.y) << 16);
            unsigned w1 = (unsigned)f2bf(a0.z) | ((unsigned)f2bf(a0.w) << 16);
            unsigned w2 = (unsigned)f2bf(a1.x) | ((unsigned)f2bf(a1.y) << 16);
            unsigned w3 = (unsigned)f2bf(a1.z) | ((unsigned)f2bf(a1.w) << 16);
            int rx = (i & 7) << 4;
            int o0 = (i * 512 + 256 + li * 8) ^ rx;
            int o1 = (i * 512 + 256 + 128 + li * 8) ^ rx;
            *(uint2*)((char*)x2s + o0) = make_uint2(w0, w1);
            *(uint2*)((char*)x2s + o1) = make_uint2(w2, w3);
        }
    }
    __syncthreads();

    // phase 2: [64x256] @ [256x128] via mfma_f32_16x16x32_bf16. Wave w -> rows [w*16, w*16+16).
    int lane = tid & 63, w = tid >> 6;
    int colb = lane & 15, kg = lane >> 4;

    u32x4 araw[8];
    {
        int row  = w * 16 + colb;
        int base = row * 512 + kg * 16;
        int rx   = (row & 7) << 4;
        #pragma unroll
        for (int ks = 0; ks < 8; ks++) {
            int byteoff = (base + ks * 64) ^ rx;
            araw[ks] = *(const u32x4*)((const char*)x2s + byteoff);
        }
    }

    f32x4 acc[8];
    #pragma unroll
    for (int cb = 0; cb < 8; cb++) acc[cb] = 0.0f;

    #pragma unroll
    for (int cb = 0; cb < 8; cb++) {
        const unsigned short* wp = Wt + ((cb * 16 + colb) * 256 + kg * 8);
        #pragma unroll
        for (int ks = 0; ks < 8; ks++) {
            u32x4 braw = *(const u32x4*)(wp + ks * 32);
            acc[cb] = __builtin_amdgcn_mfma_f32_16x16x32_bf16(
                __builtin_bit_cast(bf16x8, araw[ks]),
                __builtin_bit_cast(bf16x8, braw), acc[cb], 0, 0, 0);
        }
    }

    // epilogue: +bias, LayerNorm (16-lane shfl reduce), ELU, residual, heads
    #pragma unroll
    for (int j = 0; j < 4; j++) {
        float hv[8];
        float sum = 0.f, sq = 0.f;
        #pragma unroll
        for (int cb = 0; cb < 8; cb++) {
            float h = acc[cb][j] + bconv[cb * 16 + colb];
            hv[cb] = h; sum += h; sq += h * h;
        }
        #pragma unroll
        for (int m = 1; m < 16; m <<= 1) {
            sum += __shfl_xor(sum, m);
            sq  += __shfl_xor(sq, m);
        }
        float mean = sum * (1.f / 128.f);
        float var  = sq * (1.f / 128.f) - mean * mean;
        float rs   = rsqrtf(var + 1e-5f);
        int grow = rowbase + w * 16 + kg * 4 + j;     // uniform across the 16-lane group
        if (grow < N_NODES) {
            float bl = 0.f;
            #pragma unroll
            for (int cb = 0; cb < 8; cb++) {
                int col  = cb * 16 + colb;
                float hn = (hv[cb] - mean) * rs * gamma[col] + beta[col];
                hn = hn > 0.f ? hn : (expf(hn) - 1.f);
                float xo = hn + xin[(size_t)grow * DIM + col];
                xout[(size_t)grow * DIM + col] = xo;
                if (xbnext) xbnext[(size_t)grow * DIM + col] = f2bf(xo);
                bl += xo * bW[col];
            }
            if (last) {
                #pragma unroll
                for (int m = 1; m < 16; m <<= 1) bl += __shfl_xor(bl, m);
                if (colb == 0) boundary[grow] = bl + bb[0];
            }
        }
    }
}

// ---------------- mean-pool per graph (batch is sorted) ----------------

__global__ void k_pool(const float* __restrict__ x, const int* __restrict__ batch,
                       float* __restrict__ pooled, int* __restrict__ gcount) {
    __shared__ float s[128];
    int g = blockIdx.x >> 4, q = blockIdx.x & 15;
    int lo = 0, hi = N_NODES;
    while (lo < hi) { int m = (lo + hi) >> 1; if (batch[m] < g) lo = m + 1; else hi = m; }
    int s0 = lo;
    lo = 0; hi = N_NODES;
    while (lo < hi) { int m = (lo + hi) >> 1; if (batch[m] < g + 1) lo = m + 1; else hi = m; }
    int e0  = lo;
    int len = e0 - s0;
    int r0 = s0 + (int)((long long)len * q / 16);
    int r1 = s0 + (int)((long long)len * (q + 1) / 16);
    int col = threadIdx.x & 127, half = threadIdx.x >> 7;
    float acc = 0.f;
    for (int r = r0 + half; r < r1; r += 2) acc += x[(size_t)r * DIM + col];
    if (half) s[col] = acc;
    __syncthreads();
    if (!half) {
        acc += s[col];
        atomicAdd(&pooled[g * DIM + col], acc);
    }
    if (q == 0 && threadIdx.x == 0) gcount[g] = len;
}

// ---------------- domain head MLP (tiny) ----------------

__global__ __launch_bounds__(256) void k_mlp(
    const float* __restrict__ pooled, const int* __restrict__ gcount,
    const float* __restrict__ W1, const float* __restrict__ b1,
    const float* __restrict__ W2, const float* __restrict__ b2,
    float* __restrict__ out)
{
    __shared__ float pm[64 * 128];
    __shared__ float h1[64 * 64];
    int tid = threadIdx.x;
    for (int idx = tid; idx < 64 * 128; idx += 256) {
        int g = idx >> 7;
        float cnt = (float)gcount[g];
        if (cnt < 1.f) cnt = 1.f;
        pm[idx] = pooled[idx] / cnt;
    }
    __syncthreads();
    {
        int i = tid & 63, jg = tid >> 6;
        for (int jj = 0; jj < 16; jj++) {
            int j = jg * 16 + jj;
            float s = b1[j];
            for (int k = 0; k < 128; k++) s += pm[i * 128 + k] * W1[k * 64 + j];
            h1[i * 64 + j] = s > 0.f ? s : (expf(s) - 1.f);
        }
    }
    __syncthreads();
    for (int o = tid; o < 64 * N_PATIENTS; o += 256) {
        int i = o / N_PATIENTS, p = o - i * N_PATIENTS;
        float s = b2[p];
        for (int k = 0; k < 64; k++) s += h1[i * 64 + k] * W2[k * N_PATIENTS + p];
        out[o] = s;
    }
}

// ---------------- launch ----------------

extern "C" void kernel_launch(void* const* d_in, const int* in_sizes, int n_in,
                              void* d_out, int out_size, void* d_ws, size_t ws_size,
                              hipStream_t stream) {
    const float* x     = (const float*)d_in[0];
    const int*   ei    = (const int*)d_in[1];
    const int*   batch = (const int*)d_in[2];
    const float* Wroot = (const float*)d_in[3];
    const float* Wrel  = (const float*)d_in[4];
    const float* bconv = (const float*)d_in[5];
    const float* gamma = (const float*)d_in[6];
    const float* beta  = (const float*)d_in[7];
    const float* bW    = (const float*)d_in[8];
    const float* bb    = (const float*)d_in[9];
    const float* W1    = (const float*)d_in[10];
    const float* b1    = (const float*)d_in[11];
    const float* W2    = (const float*)d_in[12];
    const float* b2    = (const float*)d_in[13];
    float* out = (float*)d_out;

    char* ws = (char*)d_ws;
    size_t off = 0;
    auto alloc = [&](size_t bytes) -> char* {
        char* p = ws + off;
        off += (bytes + 255) & ~(size_t)255;
        return p;
    };
    float*          xA      = (float*)alloc((size_t)N_NODES * DIM * 4);
    float*          xB      = (float*)alloc((size_t)N_NODES * DIM * 4);
    unsigned short* xbA     = (unsigned short*)alloc((size_t)N_NODES * DIM * 2);
    unsigned short* xbB     = (unsigned short*)alloc((size_t)N_NODES * DIM * 2);
    unsigned short* Wt      = (unsigned short*)alloc((size_t)NLAYERS * DIM * 256 * 2);
    int*            counts  = (int*)alloc((size_t)N_NODES * 4);
    int*            incl    = (int*)alloc((size_t)N_NODES * 4);
    int*            row_ptr = (int*)alloc((size_t)(N_NODES + 1) * 4);
    int*            cursor  = (int*)alloc((size_t)N_NODES * 4);
    int*            esorted = (int*)alloc((size_t)N_EDGES * 4);
    int*            bsums   = (int*)alloc(256 * 4);
    float*          pooled  = (float*)alloc((size_t)N_GRAPHS * DIM * 4);
    int*            gcount  = (int*)alloc((size_t)N_GRAPHS * 4);
    (void)ws_size; (void)in_sizes; (void)n_in; (void)out_size;

    hipMemsetAsync(counts, 0, (size_t)N_NODES * 4, stream);
    hipMemsetAsync(pooled, 0, (size_t)N_GRAPHS * DIM * 4, stream);

    k_wt<<<(NLAYERS * DIM * 256 + 255) / 256, 256, 0, stream>>>(Wroot, Wrel, Wt);
    k_prep<<<(N_NODES * DIM / 8 + 255) / 256, 256, 0, stream>>>(x, xbA);
    k_count<<<(N_EDGES + 255) / 256, 256, 0, stream>>>(ei, counts);
    int nb = (N_NODES + 255) / 256;
    k_scan_a<<<nb, 256, 0, stream>>>(counts, incl, bsums, N_NODES);
    k_scan_b<<<1, 256, 0, stream>>>(bsums, nb);
    k_scan_c<<<nb, 256, 0, stream>>>(counts, incl, bsums, row_ptr, cursor, N_NODES);
    k_fill<<<(N_EDGES + 255) / 256, 256, 0, stream>>>(ei, cursor, esorted);

    int lgrid = (N_NODES + 63) / 64;
    const float* xi = x;
    float* xo = xA;
    const unsigned short* xbi = xbA;
    unsigned short* xbo = xbB;
    for (int l = 0; l < NLAYERS; l++) {
        int last = (l == NLAYERS - 1);
        k_layer<<<lgrid, 256, 0, stream>>>(xi, xo, xbi, last ? nullptr : xbo,
                                           row_ptr, esorted, Wt + (size_t)l * DIM * 256,
                                           bconv + l * DIM, gamma + l * DIM, beta + l * DIM,
                                           bW, bb, out, last);
        xi = xo;
        xo = (xo == xA) ? xB : xA;
        const unsigned short* t = xbi; xbi = xbo; xbo = (unsigned short*)t;
    }
    const float* xf = xi;
    k_pool<<<N_GRAPHS * 16, 256, 0, stream>>>(xf, batch, pooled, gcount);
    k_mlp<<<1, 256, 0, stream>>>(pooled, gcount, W1, b1, W2, b2, out + N_NODES);
}

// Round 3
// 360.149 us; speedup vs baseline: 2.0339x; 1.2538x over previous
//
#include <hip/hip_runtime.h>
#include <cstdint>
#include <cstddef>

#define N_NODES   50000
#define N_EDGES   600000
#define DIM       128
#define NLAYERS   4
#define N_GRAPHS  64
#define N_PATIENTS 50

typedef __attribute__((ext_vector_type(8))) __bf16        bf16x8;
typedef __attribute__((ext_vector_type(4))) float         f32x4;
typedef __attribute__((ext_vector_type(4))) unsigned int  u32x4;
typedef __attribute__((ext_vector_type(8))) unsigned short u16x8;

__device__ inline unsigned short f2bf(float f) {
    unsigned u = __builtin_bit_cast(unsigned, f);
    u += 0x7FFFu + ((u >> 16) & 1u);   // round-to-nearest-even
    return (unsigned short)(u >> 16);
}

__device__ inline float bf2f(unsigned short s) {
    return __builtin_bit_cast(float, (unsigned)s << 16);
}

__device__ inline f32x4 lo4(u16x8 u) {
    f32x4 r;
    r[0] = bf2f(u[0]); r[1] = bf2f(u[1]); r[2] = bf2f(u[2]); r[3] = bf2f(u[3]);
    return r;
}
__device__ inline f32x4 hi4(u16x8 u) {
    f32x4 r;
    r[0] = bf2f(u[4]); r[1] = bf2f(u[5]); r[2] = bf2f(u[6]); r[3] = bf2f(u[7]);
    return r;
}

// ---------------- CSR build ----------------

__global__ void k_count(const int* __restrict__ ei, int* __restrict__ counts) {
    int e = blockIdx.x * 256 + threadIdx.x;
    if (e < N_EDGES) atomicAdd(&counts[ei[N_EDGES + e]], 1);
}

__global__ void k_scan_a(const int* __restrict__ counts, int* __restrict__ incl,
                         int* __restrict__ bsums, int n) {
    __shared__ int s[256];
    int i = blockIdx.x * 256 + threadIdx.x;
    int v = (i < n) ? counts[i] : 0;
    s[threadIdx.x] = v;
    __syncthreads();
    for (int off = 1; off < 256; off <<= 1) {
        int t = (threadIdx.x >= off) ? s[threadIdx.x - off] : 0;
        __syncthreads();
        s[threadIdx.x] += t;
        __syncthreads();
    }
    if (i < n) incl[i] = s[threadIdx.x];
    if (threadIdx.x == 255) bsums[blockIdx.x] = s[255];
}

__global__ void k_scan_b(int* __restrict__ bsums, int nb) {
    __shared__ int s[256];
    int t = threadIdx.x;
    int v = (t < nb) ? bsums[t] : 0;
    s[t] = v;
    __syncthreads();
    for (int off = 1; off < 256; off <<= 1) {
        int u = (t >= off) ? s[t - off] : 0;
        __syncthreads();
        s[t] += u;
        __syncthreads();
    }
    if (t < nb) bsums[t] = s[t];
}

__global__ void k_scan_c(const int* __restrict__ counts, const int* __restrict__ incl,
                         const int* __restrict__ bsums, int* __restrict__ row_ptr,
                         int* __restrict__ cursor, int n) {
    int i = blockIdx.x * 256 + threadIdx.x;
    if (i < n) {
        int off = blockIdx.x ? bsums[blockIdx.x - 1] : 0;
        int ex  = incl[i] - counts[i] + off;
        row_ptr[i] = ex;
        cursor[i]  = ex;
        if (i == n - 1) row_ptr[n] = incl[i] + off;
    }
}

__global__ void k_fill(const int* __restrict__ ei, int* __restrict__ cursor,
                       int* __restrict__ esorted) {
    int e = blockIdx.x * 256 + threadIdx.x;
    if (e < N_EDGES) {
        int d   = ei[N_EDGES + e];
        int pos = atomicAdd(&cursor[d], 1);
        esorted[pos] = ei[e];
    }
}

// ---------------- x -> bf16 copy ----------------

__global__ void k_prep(const float* __restrict__ x, unsigned short* __restrict__ xb) {
    int idx = blockIdx.x * 256 + threadIdx.x;        // one u16x8 per thread
    if (idx < N_NODES * DIM / 8) {
        f32x4 v0 = *(const f32x4*)(x + (size_t)idx * 8);
        f32x4 v1 = *(const f32x4*)(x + (size_t)idx * 8 + 4);
        u16x8 o = { f2bf(v0[0]), f2bf(v0[1]), f2bf(v0[2]), f2bf(v0[3]),
                    f2bf(v1[0]), f2bf(v1[1]), f2bf(v1[2]), f2bf(v1[3]) };
        *(u16x8*)(xb + (size_t)idx * 8) = o;
    }
}

// ---------------- W precombine: Wt[l][c][k] = bf16(Wcat[k][c]) ----------------

__global__ void k_wt(const float* __restrict__ Wroot, const float* __restrict__ Wrel,
                     unsigned short* __restrict__ Wt) {
    int idx = blockIdx.x * 256 + threadIdx.x;   // l*32768 + c*256 + k
    if (idx < NLAYERS * DIM * 256) {
        int l = idx >> 15;
        int c = (idx >> 8) & 127;
        int k = idx & 255;
        float v = (k < 128) ? Wroot[l * 16384 + k * 128 + c]
                            : Wrel[l * 16384 + (k - 128) * 128 + c];
        Wt[idx] = f2bf(v);
    }
}

// ---------------- fused layer (512 threads, 64 rows) ----------------

__global__ __launch_bounds__(512) void k_layer(
    const float* __restrict__ xin, float* __restrict__ xout,
    const unsigned short* __restrict__ xb,        // bf16 copy of xin
    unsigned short* __restrict__ xbnext,          // bf16 copy of xout (may be null)
    const int* __restrict__ row_ptr, const int* __restrict__ esrc,
    const unsigned short* __restrict__ Wt,        // [128][256] bf16, linear
    const float* __restrict__ bconv, const float* __restrict__ gamma,
    const float* __restrict__ beta,
    const float* __restrict__ bW, const float* __restrict__ bb,
    float* __restrict__ boundary, int last)
{
    __shared__ __align__(16) unsigned short x2s[64 * 256];   // 32 KB, XOR-swizzled
    __shared__ float rsum[64][2], rsq[64][2], rbl[64][2];
    const int tid     = threadIdx.x;
    const int rowbase = blockIdx.x * 64;

    // phase 1a: x rows (bf16) -> LDS cols [0,128). 8 threads per row.
    {
        int r = tid >> 3, q = tid & 7;
        int grow = rowbase + r;
        int rx = (r & 7) << 4;
        if (grow < N_NODES) {
            const unsigned short* xp = xb + (size_t)grow * DIM + q * 16;
            #pragma unroll
            for (int c = 0; c < 2; c++) {
                u16x8 v = *(const u16x8*)(xp + c * 8);
                int byteoff = (r * 512 + q * 32 + c * 16) ^ rx;
                *(u16x8*)((char*)x2s + byteoff) = v;
            }
        } else {
            u16x8 z = { 0, 0, 0, 0, 0, 0, 0, 0 };
            #pragma unroll
            for (int c = 0; c < 2; c++) {
                int byteoff = (r * 512 + q * 32 + c * 16) ^ rx;
                *(u16x8*)((char*)x2s + byteoff) = z;
            }
        }
    }

    // phase 1b: CSR neighbor-sum -> LDS cols [128,256).
    // Row per 16-lane group (full 256B row in one u16x8 load/lane),
    // 4 rows concurrent per wave, 2 serial, 4-edge unroll.
    {
        int w = tid >> 6, lane = tid & 63;
        int kg = lane >> 4, li = lane & 15;
        #pragma unroll
        for (int rr = 0; rr < 2; ++rr) {
            int i = w * 8 + kg * 2 + rr;          // local row
            int grow = rowbase + i;
            f32x4 a0 = 0.f, a1 = 0.f, b0 = 0.f, b1 = 0.f;
            int beg = 0, end = 0;
            if (grow < N_NODES) { beg = row_ptr[grow]; end = row_ptr[grow + 1]; }
            int e = beg;
            for (; e + 3 < end; e += 4) {
                int s0 = esrc[e], s1 = esrc[e + 1], s2 = esrc[e + 2], s3 = esrc[e + 3];
                u16x8 u0 = *(const u16x8*)(xb + (size_t)s0 * DIM + li * 8);
                u16x8 u1 = *(const u16x8*)(xb + (size_t)s1 * DIM + li * 8);
                u16x8 u2 = *(const u16x8*)(xb + (size_t)s2 * DIM + li * 8);
                u16x8 u3 = *(const u16x8*)(xb + (size_t)s3 * DIM + li * 8);
                a0 += lo4(u0); a1 += hi4(u0);
                b0 += lo4(u1); b1 += hi4(u1);
                a0 += lo4(u2); a1 += hi4(u2);
                b0 += lo4(u3); b1 += hi4(u3);
            }
            for (; e < end; ++e) {
                int s0 = esrc[e];
                u16x8 u0 = *(const u16x8*)(xb + (size_t)s0 * DIM + li * 8);
                a0 += lo4(u0); a1 += hi4(u0);
            }
            a0 += b0; a1 += b1;
            u16x8 o = { f2bf(a0[0]), f2bf(a0[1]), f2bf(a0[2]), f2bf(a0[3]),
                        f2bf(a1[0]), f2bf(a1[1]), f2bf(a1[2]), f2bf(a1[3]) };
            int byteoff = (i * 512 + 256 + li * 16) ^ ((i & 7) << 4);
            *(u16x8*)((char*)x2s + byteoff) = o;
        }
    }
    __syncthreads();

    // phase 2: [64x256] @ [256x128]. Wave w: rowtile rt = w>>1, colhalf ch = w&1.
    int lane = tid & 63, w = tid >> 6;
    int colb = lane & 15, kg = lane >> 4;
    int rt = w >> 1, ch = w & 1;

    u32x4 araw[8];
    {
        int row  = rt * 16 + colb;
        int base = row * 512 + kg * 16;
        int rx   = (row & 7) << 4;
        #pragma unroll
        for (int ks = 0; ks < 8; ks++) {
            int byteoff = (base + ks * 64) ^ rx;
            araw[ks] = *(const u32x4*)((const char*)x2s + byteoff);
        }
    }

    f32x4 acc[4];
    #pragma unroll
    for (int cb = 0; cb < 4; cb++) acc[cb] = 0.0f;

    #pragma unroll
    for (int cb = 0; cb < 4; cb++) {
        const unsigned short* wp = Wt + ((ch * 64 + cb * 16 + colb) * 256 + kg * 8);
        #pragma unroll
        for (int ks = 0; ks < 8; ks++) {
            u32x4 braw = *(const u32x4*)(wp + ks * 32);
            acc[cb] = __builtin_amdgcn_mfma_f32_16x16x32_bf16(
                __builtin_bit_cast(bf16x8, araw[ks]),
                __builtin_bit_cast(bf16x8, braw), acc[cb], 0, 0, 0);
        }
    }

    // epilogue part 1: per-row partial sums (64 cols per wave) -> LDS slots
    float hv[4][4];
    #pragma unroll
    for (int j = 0; j < 4; j++) {
        float ps = 0.f, pq = 0.f;
        #pragma unroll
        for (int cb = 0; cb < 4; cb++) {
            int col = ch * 64 + cb * 16 + colb;
            float h = acc[cb][j] + bconv[col];
            hv[j][cb] = h; ps += h; pq += h * h;
        }
        #pragma unroll
        for (int m = 1; m < 16; m <<= 1) {
            ps += __shfl_xor(ps, m);
            pq += __shfl_xor(pq, m);
        }
        if (colb == 0) {
            int lr = rt * 16 + kg * 4 + j;
            rsum[lr][ch] = ps;
            rsq[lr][ch]  = pq;
        }
    }
    __syncthreads();

    // epilogue part 2: LN, ELU, residual, stores, boundary partials
    #pragma unroll
    for (int j = 0; j < 4; j++) {
        int lr   = rt * 16 + kg * 4 + j;
        int grow = rowbase + lr;
        float sum = rsum[lr][0] + rsum[lr][1];
        float sq  = rsq[lr][0] + rsq[lr][1];
        float mean = sum * (1.f / 128.f);
        float var  = sq * (1.f / 128.f) - mean * mean;
        float rs   = rsqrtf(var + 1e-5f);
        float bl = 0.f;
        if (grow < N_NODES) {
            #pragma unroll
            for (int cb = 0; cb < 4; cb++) {
                int col  = ch * 64 + cb * 16 + colb;
                float hn = (hv[j][cb] - mean) * rs * gamma[col] + beta[col];
                hn = hn > 0.f ? hn : (expf(hn) - 1.f);
                float xo = hn + xin[(size_t)grow * DIM + col];
                xout[(size_t)grow * DIM + col] = xo;
                if (xbnext) xbnext[(size_t)grow * DIM + col] = f2bf(xo);
                bl += xo * bW[col];
            }
        }
        if (last) {
            #pragma unroll
            for (int m = 1; m < 16; m <<= 1) bl += __shfl_xor(bl, m);
            if (colb == 0) rbl[lr][ch] = bl;
        }
    }
    if (last) {
        __syncthreads();
        if (tid < 64 && rowbase + tid < N_NODES)
            boundary[rowbase + tid] = rbl[tid][0] + rbl[tid][1] + bb[0];
    }
}

// ---------------- mean-pool per graph (batch is sorted) ----------------

__global__ void k_pool(const float* __restrict__ x, const int* __restrict__ batch,
                       float* __restrict__ pooled, int* __restrict__ gcount) {
    __shared__ float s[128];
    int g = blockIdx.x >> 4, q = blockIdx.x & 15;
    int lo = 0, hi = N_NODES;
    while (lo < hi) { int m = (lo + hi) >> 1; if (batch[m] < g) lo = m + 1; else hi = m; }
    int s0 = lo;
    lo = 0; hi = N_NODES;
    while (lo < hi) { int m = (lo + hi) >> 1; if (batch[m] < g + 1) lo = m + 1; else hi = m; }
    int e0  = lo;
    int len = e0 - s0;
    int r0 = s0 + (int)((long long)len * q / 16);
    int r1 = s0 + (int)((long long)len * (q + 1) / 16);
    int col = threadIdx.x & 127, half = threadIdx.x >> 7;
    float acc = 0.f;
    for (int r = r0 + half; r < r1; r += 2) acc += x[(size_t)r * DIM + col];
    if (half) s[col] = acc;
    __syncthreads();
    if (!half) {
        acc += s[col];
        atomicAdd(&pooled[g * DIM + col], acc);
    }
    if (q == 0 && threadIdx.x == 0) gcount[g] = len;
}

// ---------------- domain head: thread-per-output, no LDS ----------------

__global__ __launch_bounds__(256) void k_dom1(
    const float* __restrict__ pooled, const int* __restrict__ gcount,
    const float* __restrict__ W1, const float* __restrict__ b1,
    float* __restrict__ h1g)
{
    int o = blockIdx.x * 256 + threadIdx.x;       // 64*64 outputs
    if (o < 64 * 64) {
        int i = o >> 6, j = o & 63;
        float cnt = (float)gcount[i];
        float rc = 1.f / (cnt < 1.f ? 1.f : cnt);
        float s = b1[j];
        #pragma unroll 8
        for (int k = 0; k < 128; k++) s += pooled[i * 128 + k] * rc * W1[k * 64 + j];
        h1g[o] = s > 0.f ? s : (expf(s) - 1.f);
    }
}

__global__ __launch_bounds__(256) void k_dom2(
    const float* __restrict__ h1g,
    const float* __restrict__ W2, const float* __restrict__ b2,
    float* __restrict__ out)
{
    int o = blockIdx.x * 256 + threadIdx.x;       // 64*50 outputs
    if (o < 64 * N_PATIENTS) {
        int i = o / N_PATIENTS, p = o - i * N_PATIENTS;
        float s = b2[p];
        #pragma unroll 8
        for (int k = 0; k < 64; k++) s += h1g[i * 64 + k] * W2[k * N_PATIENTS + p];
        out[o] = s;
    }
}

// ---------------- launch ----------------

extern "C" void kernel_launch(void* const* d_in, const int* in_sizes, int n_in,
                              void* d_out, int out_size, void* d_ws, size_t ws_size,
                              hipStream_t stream) {
    const float* x     = (const float*)d_in[0];
    const int*   ei    = (const int*)d_in[1];
    const int*   batch = (const int*)d_in[2];
    const float* Wroot = (const float*)d_in[3];
    const float* Wrel  = (const float*)d_in[4];
    const float* bconv = (const float*)d_in[5];
    const float* gamma = (const float*)d_in[6];
    const float* beta  = (const float*)d_in[7];
    const float* bW    = (const float*)d_in[8];
    const float* bb    = (const float*)d_in[9];
    const float* W1    = (const float*)d_in[10];
    const float* b1    = (const float*)d_in[11];
    const float* W2    = (const float*)d_in[12];
    const float* b2    = (const float*)d_in[13];
    float* out = (float*)d_out;

    char* ws = (char*)d_ws;
    size_t off = 0;
    auto alloc = [&](size_t bytes) -> char* {
        char* p = ws + off;
        off += (bytes + 255) & ~(size_t)255;
        return p;
    };
    float*          xA      = (float*)alloc((size_t)N_NODES * DIM * 4);
    float*          xB      = (float*)alloc((size_t)N_NODES * DIM * 4);
    unsigned short* xbA     = (unsigned short*)alloc((size_t)N_NODES * DIM * 2);
    unsigned short* xbB     = (unsigned short*)alloc((size_t)N_NODES * DIM * 2);
    unsigned short* Wt      = (unsigned short*)alloc((size_t)NLAYERS * DIM * 256 * 2);
    int*            counts  = (int*)alloc((size_t)N_NODES * 4);
    int*            incl    = (int*)alloc((size_t)N_NODES * 4);
    int*            row_ptr = (int*)alloc((size_t)(N_NODES + 1) * 4);
    int*            cursor  = (int*)alloc((size_t)N_NODES * 4);
    int*            esorted = (int*)alloc((size_t)N_EDGES * 4);
    int*            bsums   = (int*)alloc(256 * 4);
    float*          pooled  = (float*)alloc((size_t)N_GRAPHS * DIM * 4);
    int*            gcount  = (int*)alloc((size_t)N_GRAPHS * 4);
    float*          h1g     = (float*)alloc((size_t)64 * 64 * 4);
    (void)ws_size; (void)in_sizes; (void)n_in; (void)out_size;

    hipMemsetAsync(counts, 0, (size_t)N_NODES * 4, stream);
    hipMemsetAsync(pooled, 0, (size_t)N_GRAPHS * DIM * 4, stream);

    k_wt<<<(NLAYERS * DIM * 256 + 255) / 256, 256, 0, stream>>>(Wroot, Wrel, Wt);
    k_prep<<<(N_NODES * DIM / 8 + 255) / 256, 256, 0, stream>>>(x, xbA);
    k_count<<<(N_EDGES + 255) / 256, 256, 0, stream>>>(ei, counts);
    int nb = (N_NODES + 255) / 256;
    k_scan_a<<<nb, 256, 0, stream>>>(counts, incl, bsums, N_NODES);
    k_scan_b<<<1, 256, 0, stream>>>(bsums, nb);
    k_scan_c<<<nb, 256, 0, stream>>>(counts, incl, bsums, row_ptr, cursor, N_NODES);
    k_fill<<<(N_EDGES + 255) / 256, 256, 0, stream>>>(ei, cursor, esorted);

    int lgrid = (N_NODES + 63) / 64;
    const float* xi = x;
    float* xo = xA;
    const unsigned short* xbi = xbA;
    unsigned short* xbo = xbB;
    for (int l = 0; l < NLAYERS; l++) {
        int last = (l == NLAYERS - 1);
        k_layer<<<lgrid, 512, 0, stream>>>(xi, xo, xbi, last ? nullptr : xbo,
                                           row_ptr, esorted, Wt + (size_t)l * DIM * 256,
                                           bconv + l * DIM, gamma + l * DIM, beta + l * DIM,
                                           bW, bb, out, last);
        xi = xo;
        xo = (xo == xA) ? xB : xA;
        const unsigned short* t = xbi; xbi = xbo; xbo = (unsigned short*)t;
    }
    const float* xf = xi;
    k_pool<<<N_GRAPHS * 16, 256, 0, stream>>>(xf, batch, pooled, gcount);
    k_dom1<<<16, 256, 0, stream>>>(pooled, gcount, W1, b1, h1g);
    k_dom2<<<(64 * N_PATIENTS + 255) / 256, 256, 0, stream>>>(h1g, W2, b2, out + N_NODES);
}

// Round 4
// 318.252 us; speedup vs baseline: 2.3016x; 1.1316x over previous
//
#include <hip/hip_runtime.h>
#include <cstdint>
#include <cstddef>

#define N_NODES   50000
#define N_EDGES   600000
#define DIM       128
#define NLAYERS   4
#define N_GRAPHS  64
#define N_PATIENTS 50
#define ROWS      32

typedef __attribute__((ext_vector_type(8))) __bf16        bf16x8;
typedef __attribute__((ext_vector_type(4))) float         f32x4;
typedef __attribute__((ext_vector_type(4))) unsigned int  u32x4;
typedef __attribute__((ext_vector_type(8))) unsigned short u16x8;

__device__ inline unsigned short f2bf(float f) {
    unsigned u = __builtin_bit_cast(unsigned, f);
    u += 0x7FFFu + ((u >> 16) & 1u);   // round-to-nearest-even
    return (unsigned short)(u >> 16);
}

__device__ inline float bf2f(unsigned short s) {
    return __builtin_bit_cast(float, (unsigned)s << 16);
}

__device__ inline f32x4 lo4(u16x8 u) {
    f32x4 r;
    r[0] = bf2f(u[0]); r[1] = bf2f(u[1]); r[2] = bf2f(u[2]); r[3] = bf2f(u[3]);
    return r;
}
__device__ inline f32x4 hi4(u16x8 u) {
    f32x4 r;
    r[0] = bf2f(u[4]); r[1] = bf2f(u[5]); r[2] = bf2f(u[6]); r[3] = bf2f(u[7]);
    return r;
}

// ---------------- CSR build ----------------

__global__ void k_count(const int* __restrict__ ei, int* __restrict__ counts) {
    int e = blockIdx.x * 256 + threadIdx.x;
    if (e < N_EDGES) atomicAdd(&counts[ei[N_EDGES + e]], 1);
}

__global__ void k_scan_a(const int* __restrict__ counts, int* __restrict__ incl,
                         int* __restrict__ bsums, int n) {
    __shared__ int s[256];
    int i = blockIdx.x * 256 + threadIdx.x;
    int v = (i < n) ? counts[i] : 0;
    s[threadIdx.x] = v;
    __syncthreads();
    for (int off = 1; off < 256; off <<= 1) {
        int t = (threadIdx.x >= off) ? s[threadIdx.x - off] : 0;
        __syncthreads();
        s[threadIdx.x] += t;
        __syncthreads();
    }
    if (i < n) incl[i] = s[threadIdx.x];
    if (threadIdx.x == 255) bsums[blockIdx.x] = s[255];
}

__global__ void k_scan_b(int* __restrict__ bsums, int nb) {
    __shared__ int s[256];
    int t = threadIdx.x;
    int v = (t < nb) ? bsums[t] : 0;
    s[t] = v;
    __syncthreads();
    for (int off = 1; off < 256; off <<= 1) {
        int u = (t >= off) ? s[t - off] : 0;
        __syncthreads();
        s[t] += u;
        __syncthreads();
    }
    if (t < nb) bsums[t] = s[t];
}

__global__ void k_scan_c(const int* __restrict__ counts, const int* __restrict__ incl,
                         const int* __restrict__ bsums, int* __restrict__ row_ptr,
                         int* __restrict__ cursor, int n) {
    int i = blockIdx.x * 256 + threadIdx.x;
    if (i < n) {
        int off = blockIdx.x ? bsums[blockIdx.x - 1] : 0;
        int ex  = incl[i] - counts[i] + off;
        row_ptr[i] = ex;
        cursor[i]  = ex;
        if (i == n - 1) row_ptr[n] = incl[i] + off;
    }
}

__global__ void k_fill(const int* __restrict__ ei, int* __restrict__ cursor,
                       int* __restrict__ esorted) {
    int e = blockIdx.x * 256 + threadIdx.x;
    if (e < N_EDGES) {
        int d   = ei[N_EDGES + e];
        int pos = atomicAdd(&cursor[d], 1);
        esorted[pos] = ei[e];
    }
}

// ---------------- x -> bf16 copy ----------------

__global__ void k_prep(const float* __restrict__ x, unsigned short* __restrict__ xb) {
    int idx = blockIdx.x * 256 + threadIdx.x;        // one u16x8 per thread
    if (idx < N_NODES * DIM / 8) {
        f32x4 v0 = *(const f32x4*)(x + (size_t)idx * 8);
        f32x4 v1 = *(const f32x4*)(x + (size_t)idx * 8 + 4);
        u16x8 o = { f2bf(v0[0]), f2bf(v0[1]), f2bf(v0[2]), f2bf(v0[3]),
                    f2bf(v1[0]), f2bf(v1[1]), f2bf(v1[2]), f2bf(v1[3]) };
        *(u16x8*)(xb + (size_t)idx * 8) = o;
    }
}

// ---------------- W precombine: Wt[l][c][k] = bf16(Wcat[k][c]) ----------------

__global__ void k_wt(const float* __restrict__ Wroot, const float* __restrict__ Wrel,
                     unsigned short* __restrict__ Wt) {
    int idx = blockIdx.x * 256 + threadIdx.x;   // l*32768 + c*256 + k
    if (idx < NLAYERS * DIM * 256) {
        int l = idx >> 15;
        int c = (idx >> 8) & 127;
        int k = idx & 255;
        float v = (k < 128) ? Wroot[l * 16384 + k * 128 + c]
                            : Wrel[l * 16384 + (k - 128) * 128 + c];
        Wt[idx] = f2bf(v);
    }
}

// ---------------- fused layer (256 threads, 32 rows, bf16 carry) ----------------

__global__ __launch_bounds__(256, 8) void k_layer(
    const unsigned short* __restrict__ xb,        // bf16 x (input)
    unsigned short* __restrict__ xbnext,          // bf16 x (output)
    const int* __restrict__ row_ptr, const int* __restrict__ esrc,
    const unsigned short* __restrict__ Wt,        // [128][256] bf16, linear
    const float* __restrict__ bconv, const float* __restrict__ gamma,
    const float* __restrict__ beta,
    const float* __restrict__ bW, const float* __restrict__ bb,
    float* __restrict__ boundary, int last)
{
    __shared__ __align__(16) unsigned short x2s[ROWS * 256];   // 16 KB, XOR-swizzled
    __shared__ float rsum[ROWS][2], rsq[ROWS][2], rbl[ROWS][2];
    const int tid     = threadIdx.x;
    const int rowbase = blockIdx.x * ROWS;

    // phase 1a: x rows (bf16) -> LDS cols [0,128). 8 threads per row, 32B each.
    {
        int r = tid >> 3, q = tid & 7;
        int grow = rowbase + r;
        int rx = (r & 7) << 4;
        if (grow < N_NODES) {
            const unsigned short* xp = xb + (size_t)grow * DIM + q * 16;
            #pragma unroll
            for (int c = 0; c < 2; c++) {
                u16x8 v = *(const u16x8*)(xp + c * 8);
                int byteoff = (r * 512 + q * 32 + c * 16) ^ rx;
                *(u16x8*)((char*)x2s + byteoff) = v;
            }
        } else {
            u16x8 z = { 0, 0, 0, 0, 0, 0, 0, 0 };
            #pragma unroll
            for (int c = 0; c < 2; c++) {
                int byteoff = (r * 512 + q * 32 + c * 16) ^ rx;
                *(u16x8*)((char*)x2s + byteoff) = z;
            }
        }
    }

    // phase 1b: CSR neighbor-sum -> LDS cols [128,256).
    // One row per 16-lane group (full 256B row: 16 lanes x 16B), 4 rows
    // concurrent per wave, 2 serial, 4-edge unroll.
    {
        int w = tid >> 6, lane = tid & 63;
        int kg = lane >> 4, li = lane & 15;
        #pragma unroll
        for (int rr = 0; rr < 2; ++rr) {
            int i = w * 8 + kg * 2 + rr;          // local row
            int grow = rowbase + i;
            f32x4 a0 = 0.f, a1 = 0.f, b0 = 0.f, b1 = 0.f;
            int beg = 0, end = 0;
            if (grow < N_NODES) { beg = row_ptr[grow]; end = row_ptr[grow + 1]; }
            int e = beg;
            for (; e + 3 < end; e += 4) {
                int s0 = esrc[e], s1 = esrc[e + 1], s2 = esrc[e + 2], s3 = esrc[e + 3];
                u16x8 u0 = *(const u16x8*)(xb + (size_t)s0 * DIM + li * 8);
                u16x8 u1 = *(const u16x8*)(xb + (size_t)s1 * DIM + li * 8);
                u16x8 u2 = *(const u16x8*)(xb + (size_t)s2 * DIM + li * 8);
                u16x8 u3 = *(const u16x8*)(xb + (size_t)s3 * DIM + li * 8);
                a0 += lo4(u0); a1 += hi4(u0);
                b0 += lo4(u1); b1 += hi4(u1);
                a0 += lo4(u2); a1 += hi4(u2);
                b0 += lo4(u3); b1 += hi4(u3);
            }
            for (; e < end; ++e) {
                int s0 = esrc[e];
                u16x8 u0 = *(const u16x8*)(xb + (size_t)s0 * DIM + li * 8);
                a0 += lo4(u0); a1 += hi4(u0);
            }
            a0 += b0; a1 += b1;
            u16x8 o = { f2bf(a0[0]), f2bf(a0[1]), f2bf(a0[2]), f2bf(a0[3]),
                        f2bf(a1[0]), f2bf(a1[1]), f2bf(a1[2]), f2bf(a1[3]) };
            int byteoff = (i * 512 + 256 + li * 16) ^ ((i & 7) << 4);
            *(u16x8*)((char*)x2s + byteoff) = o;
        }
    }
    __syncthreads();

    // phase 2: [32x256] @ [256x128]. Wave w: rowtile rt = w>>1, colhalf ch = w&1.
    int lane = tid & 63, w = tid >> 6;
    int colb = lane & 15, kg = lane >> 4;
    int rt = w >> 1, ch = w & 1;

    u32x4 araw[8];
    {
        int row  = rt * 16 + colb;
        int base = row * 512 + kg * 16;
        int rx   = (row & 7) << 4;
        #pragma unroll
        for (int ks = 0; ks < 8; ks++) {
            int byteoff = (base + ks * 64) ^ rx;
            araw[ks] = *(const u32x4*)((const char*)x2s + byteoff);
        }
    }

    f32x4 acc[4];
    #pragma unroll
    for (int cb = 0; cb < 4; cb++) acc[cb] = 0.0f;

    #pragma unroll
    for (int cb = 0; cb < 4; cb++) {
        const unsigned short* wp = Wt + ((ch * 64 + cb * 16 + colb) * 256 + kg * 8);
        #pragma unroll
        for (int ks = 0; ks < 8; ks++) {
            u32x4 braw = *(const u32x4*)(wp + ks * 32);
            acc[cb] = __builtin_amdgcn_mfma_f32_16x16x32_bf16(
                __builtin_bit_cast(bf16x8, araw[ks]),
                __builtin_bit_cast(bf16x8, braw), acc[cb], 0, 0, 0);
        }
    }

    // epilogue part 1: per-row partial sums (64 cols per wave) -> LDS slots
    float hv[4][4];
    #pragma unroll
    for (int j = 0; j < 4; j++) {
        float ps = 0.f, pq = 0.f;
        #pragma unroll
        for (int cb = 0; cb < 4; cb++) {
            int col = ch * 64 + cb * 16 + colb;
            float h = acc[cb][j] + bconv[col];
            hv[j][cb] = h; ps += h; pq += h * h;
        }
        #pragma unroll
        for (int m = 1; m < 16; m <<= 1) {
            ps += __shfl_xor(ps, m);
            pq += __shfl_xor(pq, m);
        }
        if (colb == 0) {
            int lr = rt * 16 + kg * 4 + j;
            rsum[lr][ch] = ps;
            rsq[lr][ch]  = pq;
        }
    }
    __syncthreads();

    // epilogue part 2: LN, ELU, residual (from LDS bf16), bf16 store, boundary
    #pragma unroll
    for (int j = 0; j < 4; j++) {
        int lr   = rt * 16 + kg * 4 + j;
        int grow = rowbase + lr;
        float sum = rsum[lr][0] + rsum[lr][1];
        float sq  = rsq[lr][0] + rsq[lr][1];
        float mean = sum * (1.f / 128.f);
        float var  = sq * (1.f / 128.f) - mean * mean;
        float rs   = rsqrtf(var + 1e-5f);
        float bl = 0.f;
        if (grow < N_NODES) {
            int rx = (lr & 7) << 4;
            #pragma unroll
            for (int cb = 0; cb < 4; cb++) {
                int col  = ch * 64 + cb * 16 + colb;
                float hn = (hv[j][cb] - mean) * rs * gamma[col] + beta[col];
                hn = hn > 0.f ? hn : (expf(hn) - 1.f);
                int xoff = (lr * 512 + col * 2) ^ rx;
                float xi = bf2f(*(const unsigned short*)((const char*)x2s + xoff));
                float xo = hn + xi;
                xbnext[(size_t)grow * DIM + col] = f2bf(xo);
                bl += xo * bW[col];
            }
        }
        if (last) {
            #pragma unroll
            for (int m = 1; m < 16; m <<= 1) bl += __shfl_xor(bl, m);
            if (colb == 0) rbl[lr][ch] = bl;
        }
    }
    if (last) {
        __syncthreads();
        if (tid < ROWS && rowbase + tid < N_NODES)
            boundary[rowbase + tid] = rbl[tid][0] + rbl[tid][1] + bb[0];
    }
}

// ---------------- mean-pool per graph (batch is sorted, x in bf16) ----------------

__global__ void k_pool(const unsigned short* __restrict__ xb, const int* __restrict__ batch,
                       float* __restrict__ pooled, int* __restrict__ gcount) {
    __shared__ float2 s[64][4];
    int g = blockIdx.x >> 4, q = blockIdx.x & 15;
    int lo = 0, hi = N_NODES;
    while (lo < hi) { int m = (lo + hi) >> 1; if (batch[m] < g) lo = m + 1; else hi = m; }
    int s0 = lo;
    lo = 0; hi = N_NODES;
    while (lo < hi) { int m = (lo + hi) >> 1; if (batch[m] < g + 1) lo = m + 1; else hi = m; }
    int e0  = lo;
    int len = e0 - s0;
    int r0 = s0 + (int)((long long)len * q / 16);
    int r1 = s0 + (int)((long long)len * (q + 1) / 16);
    int cp = threadIdx.x & 63, rp = threadIdx.x >> 6;     // col pair, 4-way row split
    float ax = 0.f, ay = 0.f;
    for (int r = r0 + rp; r < r1; r += 4) {
        unsigned u = *(const unsigned*)(xb + (size_t)r * DIM + cp * 2);
        ax += bf2f((unsigned short)(u & 0xFFFF));
        ay += bf2f((unsigned short)(u >> 16));
    }
    s[cp][rp] = make_float2(ax, ay);
    __syncthreads();
    if (rp == 0) {
        float2 v1 = s[cp][1], v2 = s[cp][2], v3 = s[cp][3];
        ax += v1.x + v2.x + v3.x;
        ay += v1.y + v2.y + v3.y;
        atomicAdd(&pooled[g * DIM + cp * 2], ax);
        atomicAdd(&pooled[g * DIM + cp * 2 + 1], ay);
    }
    if (q == 0 && threadIdx.x == 0) gcount[g] = len;
}

// ---------------- domain head: thread-per-output, no LDS ----------------

__global__ __launch_bounds__(256) void k_dom1(
    const float* __restrict__ pooled, const int* __restrict__ gcount,
    const float* __restrict__ W1, const float* __restrict__ b1,
    float* __restrict__ h1g)
{
    int o = blockIdx.x * 256 + threadIdx.x;       // 64*64 outputs
    if (o < 64 * 64) {
        int i = o >> 6, j = o & 63;
        float cnt = (float)gcount[i];
        float rc = 1.f / (cnt < 1.f ? 1.f : cnt);
        float s = b1[j];
        #pragma unroll 8
        for (int k = 0; k < 128; k++) s += pooled[i * 128 + k] * rc * W1[k * 64 + j];
        h1g[o] = s > 0.f ? s : (expf(s) - 1.f);
    }
}

__global__ __launch_bounds__(256) void k_dom2(
    const float* __restrict__ h1g,
    const float* __restrict__ W2, const float* __restrict__ b2,
    float* __restrict__ out)
{
    int o = blockIdx.x * 256 + threadIdx.x;       // 64*50 outputs
    if (o < 64 * N_PATIENTS) {
        int i = o / N_PATIENTS, p = o - i * N_PATIENTS;
        float s = b2[p];
        #pragma unroll 8
        for (int k = 0; k < 64; k++) s += h1g[i * 64 + k] * W2[k * N_PATIENTS + p];
        out[o] = s;
    }
}

// ---------------- launch ----------------

extern "C" void kernel_launch(void* const* d_in, const int* in_sizes, int n_in,
                              void* d_out, int out_size, void* d_ws, size_t ws_size,
                              hipStream_t stream) {
    const float* x     = (const float*)d_in[0];
    const int*   ei    = (const int*)d_in[1];
    const int*   batch = (const int*)d_in[2];
    const float* Wroot = (const float*)d_in[3];
    const float* Wrel  = (const float*)d_in[4];
    const float* bconv = (const float*)d_in[5];
    const float* gamma = (const float*)d_in[6];
    const float* beta  = (const float*)d_in[7];
    const float* bW    = (const float*)d_in[8];
    const float* bb    = (const float*)d_in[9];
    const float* W1    = (const float*)d_in[10];
    const float* b1    = (const float*)d_in[11];
    const float* W2    = (const float*)d_in[12];
    const float* b2    = (const float*)d_in[13];
    float* out = (float*)d_out;

    char* ws = (char*)d_ws;
    size_t off = 0;
    auto alloc = [&](size_t bytes) -> char* {
        char* p = ws + off;
        off += (bytes + 255) & ~(size_t)255;
        return p;
    };
    unsigned short* xbA     = (unsigned short*)alloc((size_t)N_NODES * DIM * 2);
    unsigned short* xbB     = (unsigned short*)alloc((size_t)N_NODES * DIM * 2);
    unsigned short* Wt      = (unsigned short*)alloc((size_t)NLAYERS * DIM * 256 * 2);
    int*            counts  = (int*)alloc((size_t)N_NODES * 4);
    int*            incl    = (int*)alloc((size_t)N_NODES * 4);
    int*            row_ptr = (int*)alloc((size_t)(N_NODES + 1) * 4);
    int*            cursor  = (int*)alloc((size_t)N_NODES * 4);
    int*            esorted = (int*)alloc((size_t)N_EDGES * 4);
    int*            bsums   = (int*)alloc(256 * 4);
    float*          pooled  = (float*)alloc((size_t)N_GRAPHS * DIM * 4);
    int*            gcount  = (int*)alloc((size_t)N_GRAPHS * 4);
    float*          h1g     = (float*)alloc((size_t)64 * 64 * 4);
    (void)ws_size; (void)in_sizes; (void)n_in; (void)out_size;

    hipMemsetAsync(counts, 0, (size_t)N_NODES * 4, stream);
    hipMemsetAsync(pooled, 0, (size_t)N_GRAPHS * DIM * 4, stream);

    k_wt<<<(NLAYERS * DIM * 256 + 255) / 256, 256, 0, stream>>>(Wroot, Wrel, Wt);
    k_prep<<<(N_NODES * DIM / 8 + 255) / 256, 256, 0, stream>>>(x, xbA);
    k_count<<<(N_EDGES + 255) / 256, 256, 0, stream>>>(ei, counts);
    int nb = (N_NODES + 255) / 256;
    k_scan_a<<<nb, 256, 0, stream>>>(counts, incl, bsums, N_NODES);
    k_scan_b<<<1, 256, 0, stream>>>(bsums, nb);
    k_scan_c<<<nb, 256, 0, stream>>>(counts, incl, bsums, row_ptr, cursor, N_NODES);
    k_fill<<<(N_EDGES + 255) / 256, 256, 0, stream>>>(ei, cursor, esorted);

    int lgrid = (N_NODES + ROWS - 1) / ROWS;
    const unsigned short* xbi = xbA;
    unsigned short* xbo = xbB;
    for (int l = 0; l < NLAYERS; l++) {
        int last = (l == NLAYERS - 1);
        k_layer<<<lgrid, 256, 0, stream>>>(xbi, xbo,
                                           row_ptr, esorted, Wt + (size_t)l * DIM * 256,
                                           bconv + l * DIM, gamma + l * DIM, beta + l * DIM,
                                           bW, bb, out, last);
        const unsigned short* t = xbi; xbi = xbo; xbo = (unsigned short*)t;
    }
    k_pool<<<N_GRAPHS * 16, 256, 0, stream>>>(xbi, batch, pooled, gcount);
    k_dom1<<<16, 256, 0, stream>>>(pooled, gcount, W1, b1, h1g);
    k_dom2<<<(64 * N_PATIENTS + 255) / 256, 256, 0, stream>>>(h1g, W2, b2, out + N_NODES);
}

// Round 5
// 315.172 us; speedup vs baseline: 2.3241x; 1.0098x over previous
//
#include <hip/hip_runtime.h>
#include <cstdint>
#include <cstddef>

#define N_NODES   50000
#define N_EDGES   600000
#define DIM       128
#define NLAYERS   4
#define N_GRAPHS  64
#define N_PATIENTS 50
#define ROWS      32

typedef __attribute__((ext_vector_type(8))) __bf16        bf16x8;
typedef __attribute__((ext_vector_type(4))) float         f32x4;
typedef __attribute__((ext_vector_type(4))) unsigned int  u32x4;
typedef __attribute__((ext_vector_type(8))) unsigned short u16x8;

__device__ inline unsigned short f2bf(float f) {
    unsigned u = __builtin_bit_cast(unsigned, f);
    u += 0x7FFFu + ((u >> 16) & 1u);   // round-to-nearest-even
    return (unsigned short)(u >> 16);
}

__device__ inline float bf2f(unsigned short s) {
    return __builtin_bit_cast(float, (unsigned)s << 16);
}

__device__ inline f32x4 lo4(u16x8 u) {
    f32x4 r;
    r[0] = bf2f(u[0]); r[1] = bf2f(u[1]); r[2] = bf2f(u[2]); r[3] = bf2f(u[3]);
    return r;
}
__device__ inline f32x4 hi4(u16x8 u) {
    f32x4 r;
    r[0] = bf2f(u[4]); r[1] = bf2f(u[5]); r[2] = bf2f(u[6]); r[3] = bf2f(u[7]);
    return r;
}

// ---------------- CSR build ----------------

__global__ void k_count(const int* __restrict__ ei, int* __restrict__ counts) {
    int e = blockIdx.x * 256 + threadIdx.x;
    if (e < N_EDGES) atomicAdd(&counts[ei[N_EDGES + e]], 1);
}

__global__ void k_scan_a(const int* __restrict__ counts, int* __restrict__ incl,
                         int* __restrict__ bsums, int n) {
    __shared__ int s[256];
    int i = blockIdx.x * 256 + threadIdx.x;
    int v = (i < n) ? counts[i] : 0;
    s[threadIdx.x] = v;
    __syncthreads();
    for (int off = 1; off < 256; off <<= 1) {
        int t = (threadIdx.x >= off) ? s[threadIdx.x - off] : 0;
        __syncthreads();
        s[threadIdx.x] += t;
        __syncthreads();
    }
    if (i < n) incl[i] = s[threadIdx.x];
    if (threadIdx.x == 255) bsums[blockIdx.x] = s[255];
}

__global__ void k_scan_b(int* __restrict__ bsums, int nb) {
    __shared__ int s[256];
    int t = threadIdx.x;
    int v = (t < nb) ? bsums[t] : 0;
    s[t] = v;
    __syncthreads();
    for (int off = 1; off < 256; off <<= 1) {
        int u = (t >= off) ? s[t - off] : 0;
        __syncthreads();
        s[t] += u;
        __syncthreads();
    }
    if (t < nb) bsums[t] = s[t];
}

__global__ void k_scan_c(const int* __restrict__ counts, const int* __restrict__ incl,
                         const int* __restrict__ bsums, int* __restrict__ row_ptr,
                         int* __restrict__ cursor, int n) {
    int i = blockIdx.x * 256 + threadIdx.x;
    if (i < n) {
        int off = blockIdx.x ? bsums[blockIdx.x - 1] : 0;
        int ex  = incl[i] - counts[i] + off;
        row_ptr[i] = ex;
        cursor[i]  = ex;
        if (i == n - 1) row_ptr[n] = incl[i] + off;
    }
}

__global__ void k_fill(const int* __restrict__ ei, int* __restrict__ cursor,
                       int* __restrict__ esorted) {
    int e = blockIdx.x * 256 + threadIdx.x;
    if (e < N_EDGES) {
        int d   = ei[N_EDGES + e];
        int pos = atomicAdd(&cursor[d], 1);
        esorted[pos] = ei[e];
    }
}

// ---------------- x -> bf16 copy ----------------

__global__ void k_prep(const float* __restrict__ x, unsigned short* __restrict__ xb) {
    int idx = blockIdx.x * 256 + threadIdx.x;        // one u16x8 per thread
    if (idx < N_NODES * DIM / 8) {
        f32x4 v0 = *(const f32x4*)(x + (size_t)idx * 8);
        f32x4 v1 = *(const f32x4*)(x + (size_t)idx * 8 + 4);
        u16x8 o = { f2bf(v0[0]), f2bf(v0[1]), f2bf(v0[2]), f2bf(v0[3]),
                    f2bf(v1[0]), f2bf(v1[1]), f2bf(v1[2]), f2bf(v1[3]) };
        *(u16x8*)(xb + (size_t)idx * 8) = o;
    }
}

// ---------------- W precombine: Wt[l][c][k] = bf16(Wcat[k][c]) ----------------

__global__ void k_wt(const float* __restrict__ Wroot, const float* __restrict__ Wrel,
                     unsigned short* __restrict__ Wt) {
    int idx = blockIdx.x * 256 + threadIdx.x;   // l*32768 + c*256 + k
    if (idx < NLAYERS * DIM * 256) {
        int l = idx >> 15;
        int c = (idx >> 8) & 127;
        int k = idx & 255;
        float v = (k < 128) ? Wroot[l * 16384 + k * 128 + c]
                            : Wrel[l * 16384 + (k - 128) * 128 + c];
        Wt[idx] = f2bf(v);
    }
}

// ---------------- fused layer (512 threads, 32 rows, bf16 carry) ----------------

__global__ __launch_bounds__(512, 8) void k_layer(
    const unsigned short* __restrict__ xb,        // bf16 x (input)
    unsigned short* __restrict__ xbnext,          // bf16 x (output)
    const int* __restrict__ row_ptr, const int* __restrict__ esrc,
    const unsigned short* __restrict__ Wt,        // [128][256] bf16, linear
    const float* __restrict__ bconv, const float* __restrict__ gamma,
    const float* __restrict__ beta,
    const float* __restrict__ bW, const float* __restrict__ bb,
    float* __restrict__ boundary, int last)
{
    __shared__ __align__(16) unsigned short x2s[ROWS * 256];   // 16 KB, XOR-swizzled
    __shared__ float rsum[ROWS][4], rsq[ROWS][4], rbl[ROWS][4];
    const int tid     = threadIdx.x;
    const int rowbase = blockIdx.x * ROWS;

    // decomposition shared by phase 1a/1b: 16-lane group per row
    const int grp = tid >> 4;          // 0..31 == local row
    const int li  = tid & 15;          // 16B slice within the 256B row

    // phase 1a: x row (bf16) -> LDS cols [0,128)
    {
        int grow = rowbase + grp;
        int rx = (grp & 7) << 4;
        u16x8 v = { 0, 0, 0, 0, 0, 0, 0, 0 };
        if (grow < N_NODES) v = *(const u16x8*)(xb + (size_t)grow * DIM + li * 8);
        int byteoff = (grp * 512 + li * 16) ^ rx;
        *(u16x8*)((char*)x2s + byteoff) = v;
    }

    // phase 1b: CSR neighbor-sum -> LDS cols [128,256).
    // One row per 16-lane group (full 256B row: 16 lanes x 16B), 6-edge unroll.
    {
        int grow = rowbase + grp;
        f32x4 a0 = 0.f, a1 = 0.f, b0 = 0.f, b1 = 0.f;
        int beg = 0, end = 0;
        if (grow < N_NODES) { beg = row_ptr[grow]; end = row_ptr[grow + 1]; }
        int e = beg;
        for (; e + 5 < end; e += 6) {
            int s0 = esrc[e],     s1 = esrc[e + 1], s2 = esrc[e + 2];
            int s3 = esrc[e + 3], s4 = esrc[e + 4], s5 = esrc[e + 5];
            u16x8 u0 = *(const u16x8*)(xb + (size_t)s0 * DIM + li * 8);
            u16x8 u1 = *(const u16x8*)(xb + (size_t)s1 * DIM + li * 8);
            u16x8 u2 = *(const u16x8*)(xb + (size_t)s2 * DIM + li * 8);
            u16x8 u3 = *(const u16x8*)(xb + (size_t)s3 * DIM + li * 8);
            u16x8 u4 = *(const u16x8*)(xb + (size_t)s4 * DIM + li * 8);
            u16x8 u5 = *(const u16x8*)(xb + (size_t)s5 * DIM + li * 8);
            a0 += lo4(u0); a1 += hi4(u0);
            b0 += lo4(u1); b1 += hi4(u1);
            a0 += lo4(u2); a1 += hi4(u2);
            b0 += lo4(u3); b1 += hi4(u3);
            a0 += lo4(u4); a1 += hi4(u4);
            b0 += lo4(u5); b1 += hi4(u5);
        }
        for (; e < end; ++e) {
            int s0 = esrc[e];
            u16x8 u0 = *(const u16x8*)(xb + (size_t)s0 * DIM + li * 8);
            a0 += lo4(u0); a1 += hi4(u0);
        }
        a0 += b0; a1 += b1;
        u16x8 o = { f2bf(a0[0]), f2bf(a0[1]), f2bf(a0[2]), f2bf(a0[3]),
                    f2bf(a1[0]), f2bf(a1[1]), f2bf(a1[2]), f2bf(a1[3]) };
        int byteoff = (grp * 512 + 256 + li * 16) ^ ((grp & 7) << 4);
        *(u16x8*)((char*)x2s + byteoff) = o;
    }
    __syncthreads();

    // phase 2: [32x256] @ [256x128]. Wave w: rowtile rt = w>>2, colquarter cq = w&3.
    int lane = tid & 63, w = tid >> 6;
    int colb = lane & 15, kg = lane >> 4;
    int rt = w >> 2, cq = w & 3;

    u32x4 araw[8];
    {
        int row  = rt * 16 + colb;
        int base = row * 512 + kg * 16;
        int rx   = (row & 7) << 4;
        #pragma unroll
        for (int ks = 0; ks < 8; ks++) {
            int byteoff = (base + ks * 64) ^ rx;
            araw[ks] = *(const u32x4*)((const char*)x2s + byteoff);
        }
    }

    f32x4 acc[2];
    acc[0] = 0.0f; acc[1] = 0.0f;

    #pragma unroll
    for (int cb = 0; cb < 2; cb++) {
        const unsigned short* wp = Wt + ((cq * 32 + cb * 16 + colb) * 256 + kg * 8);
        #pragma unroll
        for (int ks = 0; ks < 8; ks++) {
            u32x4 braw = *(const u32x4*)(wp + ks * 32);
            acc[cb] = __builtin_amdgcn_mfma_f32_16x16x32_bf16(
                __builtin_bit_cast(bf16x8, araw[ks]),
                __builtin_bit_cast(bf16x8, braw), acc[cb], 0, 0, 0);
        }
    }

    // epilogue part 1: per-row partial sums (32 cols per wave) -> LDS slots
    float hv[4][2];
    #pragma unroll
    for (int j = 0; j < 4; j++) {
        float ps = 0.f, pq = 0.f;
        #pragma unroll
        for (int cb = 0; cb < 2; cb++) {
            int col = cq * 32 + cb * 16 + colb;
            float h = acc[cb][j] + bconv[col];
            hv[j][cb] = h; ps += h; pq += h * h;
        }
        #pragma unroll
        for (int m = 1; m < 16; m <<= 1) {
            ps += __shfl_xor(ps, m);
            pq += __shfl_xor(pq, m);
        }
        if (colb == 0) {
            int lr = rt * 16 + kg * 4 + j;
            rsum[lr][cq] = ps;
            rsq[lr][cq]  = pq;
        }
    }
    __syncthreads();

    // epilogue part 2: LN, ELU, residual (from LDS bf16), bf16 store, boundary
    #pragma unroll
    for (int j = 0; j < 4; j++) {
        int lr   = rt * 16 + kg * 4 + j;
        int grow = rowbase + lr;
        float sum = rsum[lr][0] + rsum[lr][1] + rsum[lr][2] + rsum[lr][3];
        float sq  = rsq[lr][0] + rsq[lr][1] + rsq[lr][2] + rsq[lr][3];
        float mean = sum * (1.f / 128.f);
        float var  = sq * (1.f / 128.f) - mean * mean;
        float rs   = rsqrtf(var + 1e-5f);
        float bl = 0.f;
        if (grow < N_NODES) {
            int rx = (lr & 7) << 4;
            #pragma unroll
            for (int cb = 0; cb < 2; cb++) {
                int col  = cq * 32 + cb * 16 + colb;
                float hn = (hv[j][cb] - mean) * rs * gamma[col] + beta[col];
                hn = hn > 0.f ? hn : (expf(hn) - 1.f);
                int xoff = (lr * 512 + col * 2) ^ rx;
                float xi = bf2f(*(const unsigned short*)((const char*)x2s + xoff));
                float xo = hn + xi;
                xbnext[(size_t)grow * DIM + col] = f2bf(xo);
                bl += xo * bW[col];
            }
        }
        if (last) {
            #pragma unroll
            for (int m = 1; m < 16; m <<= 1) bl += __shfl_xor(bl, m);
            if (colb == 0) rbl[lr][cq] = bl;
        }
    }
    if (last) {
        __syncthreads();
        if (tid < ROWS && rowbase + tid < N_NODES)
            boundary[rowbase + tid] = rbl[tid][0] + rbl[tid][1] + rbl[tid][2] + rbl[tid][3] + bb[0];
    }
}

// ---------------- mean-pool per graph (batch is sorted, x in bf16) ----------------

__global__ void k_pool(const unsigned short* __restrict__ xb, const int* __restrict__ batch,
                       float* __restrict__ pooled, int* __restrict__ gcount) {
    __shared__ float2 s[64][4];
    int g = blockIdx.x >> 4, q = blockIdx.x & 15;
    int lo = 0, hi = N_NODES;
    while (lo < hi) { int m = (lo + hi) >> 1; if (batch[m] < g) lo = m + 1; else hi = m; }
    int s0 = lo;
    lo = 0; hi = N_NODES;
    while (lo < hi) { int m = (lo + hi) >> 1; if (batch[m] < g + 1) lo = m + 1; else hi = m; }
    int e0  = lo;
    int len = e0 - s0;
    int r0 = s0 + (int)((long long)len * q / 16);
    int r1 = s0 + (int)((long long)len * (q + 1) / 16);
    int cp = threadIdx.x & 63, rp = threadIdx.x >> 6;     // col pair, 4-way row split
    float ax = 0.f, ay = 0.f;
    for (int r = r0 + rp; r < r1; r += 4) {
        unsigned u = *(const unsigned*)(xb + (size_t)r * DIM + cp * 2);
        ax += bf2f((unsigned short)(u & 0xFFFF));
        ay += bf2f((unsigned short)(u >> 16));
    }
    s[cp][rp] = make_float2(ax, ay);
    __syncthreads();
    if (rp == 0) {
        float2 v1 = s[cp][1], v2 = s[cp][2], v3 = s[cp][3];
        ax += v1.x + v2.x + v3.x;
        ay += v1.y + v2.y + v3.y;
        atomicAdd(&pooled[g * DIM + cp * 2], ax);
        atomicAdd(&pooled[g * DIM + cp * 2 + 1], ay);
    }
    if (q == 0 && threadIdx.x == 0) gcount[g] = len;
}

// ---------------- domain head: thread-per-output, no LDS ----------------

__global__ __launch_bounds__(256) void k_dom1(
    const float* __restrict__ pooled, const int* __restrict__ gcount,
    const float* __restrict__ W1, const float* __restrict__ b1,
    float* __restrict__ h1g)
{
    int o = blockIdx.x * 256 + threadIdx.x;       // 64*64 outputs
    if (o < 64 * 64) {
        int i = o >> 6, j = o & 63;
        float cnt = (float)gcount[i];
        float rc = 1.f / (cnt < 1.f ? 1.f : cnt);
        float s = b1[j];
        #pragma unroll 8
        for (int k = 0; k < 128; k++) s += pooled[i * 128 + k] * rc * W1[k * 64 + j];
        h1g[o] = s > 0.f ? s : (expf(s) - 1.f);
    }
}

__global__ __launch_bounds__(256) void k_dom2(
    const float* __restrict__ h1g,
    const float* __restrict__ W2, const float* __restrict__ b2,
    float* __restrict__ out)
{
    int o = blockIdx.x * 256 + threadIdx.x;       // 64*50 outputs
    if (o < 64 * N_PATIENTS) {
        int i = o / N_PATIENTS, p = o - i * N_PATIENTS;
        float s = b2[p];
        #pragma unroll 8
        for (int k = 0; k < 64; k++) s += h1g[i * 64 + k] * W2[k * N_PATIENTS + p];
        out[o] = s;
    }
}

// ---------------- launch ----------------

extern "C" void kernel_launch(void* const* d_in, const int* in_sizes, int n_in,
                              void* d_out, int out_size, void* d_ws, size_t ws_size,
                              hipStream_t stream) {
    const float* x     = (const float*)d_in[0];
    const int*   ei    = (const int*)d_in[1];
    const int*   batch = (const int*)d_in[2];
    const float* Wroot = (const float*)d_in[3];
    const float* Wrel  = (const float*)d_in[4];
    const float* bconv = (const float*)d_in[5];
    const float* gamma = (const float*)d_in[6];
    const float* beta  = (const float*)d_in[7];
    const float* bW    = (const float*)d_in[8];
    const float* bb    = (const float*)d_in[9];
    const float* W1    = (const float*)d_in[10];
    const float* b1    = (const float*)d_in[11];
    const float* W2    = (const float*)d_in[12];
    const float* b2    = (const float*)d_in[13];
    float* out = (float*)d_out;

    char* ws = (char*)d_ws;
    size_t off = 0;
    auto alloc = [&](size_t bytes) -> char* {
        char* p = ws + off;
        off += (bytes + 255) & ~(size_t)255;
        return p;
    };
    unsigned short* xbA     = (unsigned short*)alloc((size_t)N_NODES * DIM * 2);
    unsigned short* xbB     = (unsigned short*)alloc((size_t)N_NODES * DIM * 2);
    unsigned short* Wt      = (unsigned short*)alloc((size_t)NLAYERS * DIM * 256 * 2);
    int*            counts  = (int*)alloc((size_t)N_NODES * 4);
    int*            incl    = (int*)alloc((size_t)N_NODES * 4);
    int*            row_ptr = (int*)alloc((size_t)(N_NODES + 1) * 4);
    int*            cursor  = (int*)alloc((size_t)N_NODES * 4);
    int*            esorted = (int*)alloc((size_t)N_EDGES * 4);
    int*            bsums   = (int*)alloc(256 * 4);
    float*          pooled  = (float*)alloc((size_t)N_GRAPHS * DIM * 4);
    int*            gcount  = (int*)alloc((size_t)N_GRAPHS * 4);
    float*          h1g     = (float*)alloc((size_t)64 * 64 * 4);
    (void)ws_size; (void)in_sizes; (void)n_in; (void)out_size;

    hipMemsetAsync(counts, 0, (size_t)N_NODES * 4, stream);
    hipMemsetAsync(pooled, 0, (size_t)N_GRAPHS * DIM * 4, stream);

    k_wt<<<(NLAYERS * DIM * 256 + 255) / 256, 256, 0, stream>>>(Wroot, Wrel, Wt);
    k_prep<<<(N_NODES * DIM / 8 + 255) / 256, 256, 0, stream>>>(x, xbA);
    k_count<<<(N_EDGES + 255) / 256, 256, 0, stream>>>(ei, counts);
    int nb = (N_NODES + 255) / 256;
    k_scan_a<<<nb, 256, 0, stream>>>(counts, incl, bsums, N_NODES);
    k_scan_b<<<1, 256, 0, stream>>>(bsums, nb);
    k_scan_c<<<nb, 256, 0, stream>>>(counts, incl, bsums, row_ptr, cursor, N_NODES);
    k_fill<<<(N_EDGES + 255) / 256, 256, 0, stream>>>(ei, cursor, esorted);

    int lgrid = (N_NODES + ROWS - 1) / ROWS;
    const unsigned short* xbi = xbA;
    unsigned short* xbo = xbB;
    for (int l = 0; l < NLAYERS; l++) {
        int last = (l == NLAYERS - 1);
        k_layer<<<lgrid, 512, 0, stream>>>(xbi, xbo,
                                           row_ptr, esorted, Wt + (size_t)l * DIM * 256,
                                           bconv + l * DIM, gamma + l * DIM, beta + l * DIM,
                                           bW, bb, out, last);
        const unsigned short* t = xbi; xbi = xbo; xbo = (unsigned short*)t;
    }
    k_pool<<<N_GRAPHS * 16, 256, 0, stream>>>(xbi, batch, pooled, gcount);
    k_dom1<<<16, 256, 0, stream>>>(pooled, gcount, W1, b1, h1g);
    k_dom2<<<(64 * N_PATIENTS + 255) / 256, 256, 0, stream>>>(h1g, W2, b2, out + N_NODES);
}